// Round 4
// baseline (1182.697 us; speedup 1.0000x reference)
//
#include <hip/hip_runtime.h>

#define B_ 128
#define S_ 200
#define D_ 1024
#define QK_ 128
#define E_ 2048
#define HE_ 4352            // 2*QK + 2*E
#define M_ (B_*S_)          // 25600
#define MPAD_ (M_+32)       // pad rows so attention's q-tile overreads stay in-bounds

typedef unsigned short u16;
typedef __attribute__((ext_vector_type(8))) short bf16x8;
typedef __attribute__((ext_vector_type(4))) float fx4;
typedef __attribute__((ext_vector_type(4))) u16  usx4;

__device__ __forceinline__ u16 f2bf(float f) {
  union { float f; unsigned u; } v; v.f = f;
  unsigned r = v.u + 0x7fffu + ((v.u >> 16) & 1u);   // RNE
  return (u16)(r >> 16);
}
__device__ __forceinline__ float bf2f(u16 u) {
  union { unsigned u; float f; } v; v.u = ((unsigned)u) << 16;
  return v.f;
}

// ---------------------------------------------------------------- weight cast
__global__ __launch_bounds__(256)
void castw_kernel(const float* __restrict__ ew, const float* __restrict__ pw,
                  u16* __restrict__ ewb, u16* __restrict__ pwb) {
  const int n1 = HE_*D_/4, n2 = D_*E_/4;
  const int stride = gridDim.x * blockDim.x;
  for (int i = blockIdx.x*blockDim.x + threadIdx.x; i < n1; i += stride) {
    fx4 v = ((const fx4*)ew)[i];
    usx4 o; o[0]=f2bf(v[0]); o[1]=f2bf(v[1]); o[2]=f2bf(v[2]); o[3]=f2bf(v[3]);
    ((usx4*)ewb)[i] = o;
  }
  for (int i = blockIdx.x*blockDim.x + threadIdx.x; i < n2; i += stride) {
    fx4 v = ((const fx4*)pw)[i];
    usx4 o; o[0]=f2bf(v[0]); o[1]=f2bf(v[1]); o[2]=f2bf(v[2]); o[3]=f2bf(v[3]);
    ((usx4*)pwb)[i] = o;
  }
}

// ---------------------------------------------------------------- LayerNorm -> bf16
__global__ __launch_bounds__(256)
void ln_kernel(const float* __restrict__ x, const float* __restrict__ gam,
               const float* __restrict__ bet, u16* __restrict__ xn) {
  const int m = blockIdx.x, t = threadIdx.x;
  const fx4 v = *(const fx4*)(x + (size_t)m*D_ + t*4);
  float s  = v[0]+v[1]+v[2]+v[3];
  float s2 = v[0]*v[0]+v[1]*v[1]+v[2]*v[2]+v[3]*v[3];
  #pragma unroll
  for (int off = 32; off; off >>= 1) { s += __shfl_down(s, off); s2 += __shfl_down(s2, off); }
  __shared__ float red[8];
  const int l = t & 63, w = t >> 6;
  if (l == 0) { red[w] = s; red[4+w] = s2; }
  __syncthreads();
  s  = red[0]+red[1]+red[2]+red[3];
  s2 = red[4]+red[5]+red[6]+red[7];
  const float mu  = s * (1.f/D_);
  const float var = s2 * (1.f/D_) - mu*mu;
  const float rs  = rsqrtf(var + 1e-5f);
  const fx4 g4 = *(const fx4*)(gam + t*4);
  const fx4 b4 = *(const fx4*)(bet + t*4);
  usx4 o;
  #pragma unroll
  for (int j = 0; j < 4; ++j) o[j] = f2bf((v[j]-mu)*rs*g4[j] + b4[j]);
  *(usx4*)(xn + (size_t)m*D_ + t*4) = o;
}

// ---------------------------------------------------------------- bf16 MFMA GEMM, B^T input
// C[M,N] = A[M,K] * Bt[N,K]^T.  128x128 tile, BK=32, 4 waves (2x2 of 64x64).
// 1D grid, XCD-aware bijective swizzle (nwg % 8 == 0 for all our grids).
// EPI 0: store bf16 C (ldc).  EPI 1: store f32 C + resid (ldc).
template<int EPI>
__global__ __launch_bounds__(256)
void gemm_bt(const u16* __restrict__ A, const u16* __restrict__ Bt,
             void* __restrict__ Cp, const float* __restrict__ resid,
             int K, int ldc, int gx) {
  const int nwg = gridDim.x;
  const int q8 = nwg >> 3;
  const int swz = (blockIdx.x & 7) * q8 + (blockIdx.x >> 3);
  const int m0 = (swz / gx) * 128, n0 = (swz % gx) * 128;
  __shared__ __align__(16) u16 As[128*32];
  __shared__ __align__(16) u16 Bs[128*32];
  const int t = threadIdx.x, l = t & 63, w = t >> 6;
  const int wr = w >> 1, wc = w & 1;
  fx4 acc[4][4] = {};
  // staging: lane l of wave w writes LDS bytes (w*16 + i*64)*64 + l*16 (linear),
  // i.e. row (i*64 + w*16 + (l>>2)), col (l&3)*8 of the [128][32] tile.
  const int srow = l >> 2, scol = (l & 3) * 8;
  const u16* agp = A  + (size_t)(m0 + w*16 + srow)*K + scol;
  const u16* bgp = Bt + (size_t)(n0 + w*16 + srow)*K + scol;
  for (int k0 = 0; k0 < K; k0 += 32) {
    #pragma unroll
    for (int i = 0; i < 2; ++i) {
      __builtin_amdgcn_global_load_lds(
        (const __attribute__((address_space(1))) unsigned int*)(agp + (size_t)i*64*K + k0),
        (__attribute__((address_space(3))) unsigned int*)(As + (w*16 + i*64)*32), 16, 0, 0);
      __builtin_amdgcn_global_load_lds(
        (const __attribute__((address_space(1))) unsigned int*)(bgp + (size_t)i*64*K + k0),
        (__attribute__((address_space(3))) unsigned int*)(Bs + (w*16 + i*64)*32), 16, 0, 0);
    }
    __syncthreads();
    bf16x8 af[4], bfv[4];
    const u16* ap = As + (wr*64 + (l & 15))*32 + (l >> 4)*8;
    const u16* bp = Bs + (wc*64 + (l & 15))*32 + (l >> 4)*8;
    #pragma unroll
    for (int i = 0; i < 4; ++i) {
      af[i]  = *(const bf16x8*)(ap + i*16*32);
      bfv[i] = *(const bf16x8*)(bp + i*16*32);
    }
    #pragma unroll
    for (int mi = 0; mi < 4; ++mi)
      #pragma unroll
      for (int ni = 0; ni < 4; ++ni)
        acc[mi][ni] = __builtin_amdgcn_mfma_f32_16x16x32_bf16(af[mi], bfv[ni], acc[mi][ni], 0, 0, 0);
    __syncthreads();
  }
  const int rb = (l >> 4)*4, cb = l & 15;
  #pragma unroll
  for (int mi = 0; mi < 4; ++mi)
    #pragma unroll
    for (int ni = 0; ni < 4; ++ni) {
      const int col = n0 + wc*64 + ni*16 + cb;
      #pragma unroll
      for (int r = 0; r < 4; ++r) {
        const int row = m0 + wr*64 + mi*16 + rb + r;
        const size_t idx = (size_t)row*ldc + col;
        if (EPI == 0) ((u16*)Cp)[idx] = f2bf(acc[mi][ni][r]);
        else          ((float*)Cp)[idx] = acc[mi][ni][r] + resid[idx];
      }
    }
}

// ---------------------------------------------------------------- fused expand+GEGLU
// For e-tile n0e in [0,2048): pass 0 computes pre tile (ew rows 2304+n0e..),
// applies exact gelu, keeps it packed bf16 in registers; pass 1 computes lin
// tile (ew rows 256+n0e..); product goes to A2 (bf16, e<1024) or Vv (f32).
// Same thread owns the same (row,col) in both passes -> no cross-lane traffic.
__global__ __launch_bounds__(256)
void fused_expand(const u16* __restrict__ A, const u16* __restrict__ Bt,
                  u16* __restrict__ A2, float* __restrict__ Vv) {
  const int nwg = gridDim.x;                 // 3200
  const int q8 = nwg >> 3;
  const int swz = (blockIdx.x & 7) * q8 + (blockIdx.x >> 3);
  const int m0 = (swz >> 4) * 128;           // gx = 16
  const int n0e = (swz & 15) * 128;
  __shared__ __align__(16) u16 As[128*32];
  __shared__ __align__(16) u16 Bs[128*32];
  const int t = threadIdx.x, l = t & 63, w = t >> 6;
  const int wr = w >> 1, wc = w & 1;
  const int srow = l >> 2, scol = (l & 3) * 8;
  const u16* agp = A + (size_t)(m0 + w*16 + srow)*D_ + scol;
  const u16* bgp_pre = Bt + (size_t)(2*QK_ + E_ + n0e + w*16 + srow)*D_ + scol;
  const u16* bgp_lin = Bt + (size_t)(2*QK_ + n0e + w*16 + srow)*D_ + scol;
  fx4 acc[4][4];
  unsigned gp[4][4][2];                      // gelu(pre) as packed bf16 pairs
  #pragma unroll
  for (int pass = 0; pass < 2; ++pass) {
    const u16* bgp = pass ? bgp_lin : bgp_pre;
    #pragma unroll
    for (int mi = 0; mi < 4; ++mi)
      #pragma unroll
      for (int ni = 0; ni < 4; ++ni) acc[mi][ni] = (fx4){0.f,0.f,0.f,0.f};
    for (int k0 = 0; k0 < D_; k0 += 32) {
      #pragma unroll
      for (int i = 0; i < 2; ++i) {
        __builtin_amdgcn_global_load_lds(
          (const __attribute__((address_space(1))) unsigned int*)(agp + (size_t)i*64*D_ + k0),
          (__attribute__((address_space(3))) unsigned int*)(As + (w*16 + i*64)*32), 16, 0, 0);
        __builtin_amdgcn_global_load_lds(
          (const __attribute__((address_space(1))) unsigned int*)(bgp + (size_t)i*64*D_ + k0),
          (__attribute__((address_space(3))) unsigned int*)(Bs + (w*16 + i*64)*32), 16, 0, 0);
      }
      __syncthreads();
      bf16x8 af[4], bfv[4];
      const u16* ap = As + (wr*64 + (l & 15))*32 + (l >> 4)*8;
      const u16* bp = Bs + (wc*64 + (l & 15))*32 + (l >> 4)*8;
      #pragma unroll
      for (int i = 0; i < 4; ++i) {
        af[i]  = *(const bf16x8*)(ap + i*16*32);
        bfv[i] = *(const bf16x8*)(bp + i*16*32);
      }
      #pragma unroll
      for (int mi = 0; mi < 4; ++mi)
        #pragma unroll
        for (int ni = 0; ni < 4; ++ni)
          acc[mi][ni] = __builtin_amdgcn_mfma_f32_16x16x32_bf16(af[mi], bfv[ni], acc[mi][ni], 0, 0, 0);
      __syncthreads();
    }
    if (pass == 0) {
      #pragma unroll
      for (int mi = 0; mi < 4; ++mi)
        #pragma unroll
        for (int ni = 0; ni < 4; ++ni)
          #pragma unroll
          for (int h = 0; h < 2; ++h) {
            float p0 = acc[mi][ni][2*h],   g0 = 0.5f*p0*(1.f + erff(p0*0.70710678f));
            float p1 = acc[mi][ni][2*h+1], g1 = 0.5f*p1*(1.f + erff(p1*0.70710678f));
            gp[mi][ni][h] = (unsigned)f2bf(g0) | ((unsigned)f2bf(g1) << 16);
          }
    }
  }
  const int rb = (l >> 4)*4, cb = l & 15;
  #pragma unroll
  for (int mi = 0; mi < 4; ++mi)
    #pragma unroll
    for (int ni = 0; ni < 4; ++ni) {
      const int colc = wc*64 + ni*16 + cb;
      #pragma unroll
      for (int r = 0; r < 4; ++r) {
        const int row = m0 + wr*64 + mi*16 + rb + r;
        const float gv = bf2f((u16)(gp[mi][ni][r>>1] >> ((r&1)*16)));
        const float v = acc[mi][ni][r] * gv;
        if (n0e < D_) A2[(size_t)row*E_ + n0e + colc] = f2bf(v);
        else          Vv[(size_t)row*D_ + (n0e - D_) + colc] = v;
      }
    }
}

// ---------------------------------------------------------------- attention
// block = (q-tile of 32 rows, batch). MFMA scores from compact QK buffer,
// fp32 softmax (8 lanes/row), fp32 PV with P broadcast from LDS + coalesced V.
__global__ __launch_bounds__(256)
void attn_kernel(const u16* __restrict__ QKb, const float* __restrict__ Vv,
                 const float* __restrict__ pbm, u16* __restrict__ A2) {
  const int b = blockIdx.y, qt = blockIdx.x;
  const int qbase = qt*32;
  const int kmax = (S_ < qbase+32) ? S_ : qbase+32;
  const int nkt = (kmax + 15) >> 4;
  const int t = threadIdx.x, l = t & 63, w = t >> 6;
  __shared__ float ScT[208][40];         // [k][qi], row stride 40 f32 (33 KB)
  float sp; { float p = pbm[0]; sp = (p > 20.f) ? p : log1pf(__expf(p)); }
  const float scale = 0.08838834764831845f;   // 1/sqrt(128)

  const int ntiles = 2*nkt;
  for (int tile = w; tile < ntiles; tile += 4) {
    const int qt16 = tile & 1, kt16 = tile >> 1;
    const int q0 = qbase + qt16*16, k0 = kt16*16;
    if (k0 > q0 + 15) continue;          // fully masked tile (zeroed in softmax tail)
    fx4 acc = {0.f, 0.f, 0.f, 0.f};
    const u16* qp = QKb + (size_t)(b*S_ + q0 + (l & 15))*256 + (l >> 4)*8;
    const u16* kp = QKb + (size_t)(b*S_ + k0 + (l & 15))*256 + QK_ + (l >> 4)*8;
    #pragma unroll
    for (int ks = 0; ks < 4; ++ks) {
      bf16x8 a  = *(const bf16x8*)(qp + ks*32);
      bf16x8 bb = *(const bf16x8*)(kp + ks*32);
      acc = __builtin_amdgcn_mfma_f32_16x16x32_bf16(a, bb, acc, 0, 0, 0);
    }
    const int kcol = k0 + (l & 15);
    #pragma unroll
    for (int r = 0; r < 4; ++r) {
      const int qg = q0 + (l >> 4)*4 + r;
      float s = acc[r]*scale + sp*(float)(kcol - qg);
      if (kcol > qg || qg >= S_ || kcol >= S_) s = -1e30f;
      ScT[kcol][qt16*16 + (l >> 4)*4 + r] = s;
    }
  }
  __syncthreads();
  {
    const int r = t >> 3, j = t & 7;     // 8 lanes per q-row
    const int qg = qbase + r;
    if (qg < S_) {
      float mx = -1e30f;
      for (int k = j; k <= qg; k += 8) mx = fmaxf(mx, ScT[k][r]);
      #pragma unroll
      for (int msk = 1; msk < 8; msk <<= 1) mx = fmaxf(mx, __shfl_xor(mx, msk));
      float sum = 0.f;
      for (int k = j; k <= qg; k += 8) { float p = __expf(ScT[k][r] - mx); ScT[k][r] = p; sum += p; }
      #pragma unroll
      for (int msk = 1; msk < 8; msk <<= 1) sum += __shfl_xor(sum, msk);
      const float inv = 1.f / sum;
      for (int k = j; k <= qg; k += 8) ScT[k][r] *= inv;
      for (int k = qg+1+j; k < kmax; k += 8) ScT[k][r] = 0.f;
    }
  }
  __syncthreads();
  // PV: wave w owns d-chunk [w*256, w*256+256); lane owns 4 d; 32 q-rows in regs.
  fx4 acc[32];
  #pragma unroll
  for (int i = 0; i < 32; ++i) acc[i] = (fx4){0.f,0.f,0.f,0.f};
  const float* vb = Vv + (size_t)b*S_*D_ + w*256 + l*4;
  for (int k = 0; k < kmax; ++k) {
    const fx4 v4 = *(const fx4*)(vb + (size_t)k*D_);
    #pragma unroll
    for (int g = 0; g < 8; ++g) {
      const fx4 p4 = *(const fx4*)&ScT[k][g*4];
      #pragma unroll
      for (int j = 0; j < 4; ++j) acc[g*4+j] += v4 * p4[j];
    }
  }
  #pragma unroll
  for (int qi = 0; qi < 32; ++qi) {
    const int qg = qbase + qi;
    if (qg < S_) {
      usx4 o;
      #pragma unroll
      for (int j = 0; j < 4; ++j) o[j] = f2bf(acc[qi][j]);
      *(usx4*)(A2 + (size_t)(b*S_ + qg)*E_ + D_ + w*256 + l*4) = o;
    }
  }
}

// ---------------------------------------------------------------- launch
extern "C" void kernel_launch(void* const* d_in, const int* in_sizes, int n_in,
                              void* d_out, int out_size, void* d_ws, size_t ws_size,
                              hipStream_t stream) {
  (void)in_sizes; (void)n_in; (void)out_size; (void)ws_size;
  const float* x   = (const float*)d_in[0];
  const float* ew  = (const float*)d_in[1];
  const float* pw  = (const float*)d_in[2];
  const float* gam = (const float*)d_in[3];
  const float* bet = (const float*)d_in[4];
  const float* pbm = (const float*)d_in[5];
  float* out = (float*)d_out;

  char* ws = (char*)d_ws;
  size_t off = 0;
  auto alloc = [&](size_t bytes) -> void* {
    void* p = ws + off; off += (bytes + 255) & ~(size_t)255; return p;
  };
  u16* xn  = (u16*)alloc((size_t)M_   * D_  * 2);   //  52.4 MB
  u16* QKb = (u16*)alloc((size_t)MPAD_* 256 * 2);   //  13.1 MB
  u16* A2  = (u16*)alloc((size_t)M_   * E_  * 2);   // 104.9 MB
  u16* ewb = (u16*)alloc((size_t)HE_  * D_  * 2);   //   8.9 MB
  u16* pwb = (u16*)alloc((size_t)D_   * E_  * 2);   //   4.2 MB  (total ~183.5 MB)
  float* Vv = out;                                  // V (f32 [M,D]) lives in d_out

  castw_kernel<<<1024, 256, 0, stream>>>(ew, pw, ewb, pwb);
  ln_kernel<<<M_, 256, 0, stream>>>(x, gam, bet, xn);
  gemm_bt<0><<<(256/128)*(M_/128), 256, 0, stream>>>(xn, ewb, QKb, nullptr, D_, 256, 256/128);
  fused_expand<<<(E_/128)*(M_/128), 256, 0, stream>>>(xn, ewb, A2, Vv);
  attn_kernel<<<dim3((S_+31)/32, B_), 256, 0, stream>>>(QKb, Vv, pbm, A2);
  gemm_bt<1><<<(D_/128)*(M_/128), 256, 0, stream>>>(A2, pwb, out, x, E_, D_, D_/128);
}

// Round 6
// 950.640 us; speedup vs baseline: 1.2441x; 1.2441x over previous
//
#include <hip/hip_runtime.h>

#define B_ 128
#define S_ 200
#define D_ 1024
#define QK_ 128
#define E_ 2048
#define HE_ 4352            // 2*QK + 2*E
#define M_ (B_*S_)          // 25600
#define MPAD_ (M_+32)       // pad rows so attention's q-tile overreads stay in-bounds

typedef unsigned short u16;
typedef __attribute__((ext_vector_type(8))) short bf16x8;
typedef __attribute__((ext_vector_type(4))) float fx4;
typedef __attribute__((ext_vector_type(4))) u16  usx4;

__device__ __forceinline__ u16 f2bf(float f) {
  union { float f; unsigned u; } v; v.f = f;
  unsigned r = v.u + 0x7fffu + ((v.u >> 16) & 1u);   // RNE
  return (u16)(r >> 16);
}
__device__ __forceinline__ float bf2f(u16 u) {
  union { unsigned u; float f; } v; v.u = ((unsigned)u) << 16;
  return v.f;
}

#define GLOAD(gptr, lptr) \
  __builtin_amdgcn_global_load_lds( \
      (const __attribute__((address_space(1))) unsigned int*)(gptr), \
      (__attribute__((address_space(3))) unsigned int*)(lptr), 16, 0, 0)

// ---------------------------------------------------------------- weight cast
__global__ __launch_bounds__(256)
void castw_kernel(const float* __restrict__ ew, const float* __restrict__ pw,
                  u16* __restrict__ ewb, u16* __restrict__ pwb) {
  const int n1 = HE_*D_/4, n2 = D_*E_/4;
  const int stride = gridDim.x * blockDim.x;
  for (int i = blockIdx.x*blockDim.x + threadIdx.x; i < n1; i += stride) {
    fx4 v = ((const fx4*)ew)[i];
    usx4 o; o[0]=f2bf(v[0]); o[1]=f2bf(v[1]); o[2]=f2bf(v[2]); o[3]=f2bf(v[3]);
    ((usx4*)ewb)[i] = o;
  }
  for (int i = blockIdx.x*blockDim.x + threadIdx.x; i < n2; i += stride) {
    fx4 v = ((const fx4*)pw)[i];
    usx4 o; o[0]=f2bf(v[0]); o[1]=f2bf(v[1]); o[2]=f2bf(v[2]); o[3]=f2bf(v[3]);
    ((usx4*)pwb)[i] = o;
  }
}

// ---------------------------------------------------------------- LayerNorm -> bf16
__global__ __launch_bounds__(256)
void ln_kernel(const float* __restrict__ x, const float* __restrict__ gam,
               const float* __restrict__ bet, u16* __restrict__ xn) {
  const int m = blockIdx.x, t = threadIdx.x;
  const fx4 v = *(const fx4*)(x + (size_t)m*D_ + t*4);
  float s  = v[0]+v[1]+v[2]+v[3];
  float s2 = v[0]*v[0]+v[1]*v[1]+v[2]*v[2]+v[3]*v[3];
  #pragma unroll
  for (int off = 32; off; off >>= 1) { s += __shfl_down(s, off); s2 += __shfl_down(s2, off); }
  __shared__ float red[8];
  const int l = t & 63, w = t >> 6;
  if (l == 0) { red[w] = s; red[4+w] = s2; }
  __syncthreads();
  s  = red[0]+red[1]+red[2]+red[3];
  s2 = red[4]+red[5]+red[6]+red[7];
  const float mu  = s * (1.f/D_);
  const float var = s2 * (1.f/D_) - mu*mu;
  const float rs  = rsqrtf(var + 1e-5f);
  const fx4 g4 = *(const fx4*)(gam + t*4);
  const fx4 b4 = *(const fx4*)(bet + t*4);
  usx4 o;
  #pragma unroll
  for (int j = 0; j < 4; ++j) o[j] = f2bf((v[j]-mu)*rs*g4[j] + b4[j]);
  *(usx4*)(xn + (size_t)m*D_ + t*4) = o;
}

// ---------------------------------------------------------------- bf16 MFMA GEMM, B^T input
// C[M,N] = A[M,K] * Bt[N,K]^T.  128x128 tile, BK=32, 4 waves (2x2 of 64x64).
// T3-minimum 2-phase: LDS dbuf, issue next tile's global_load_lds BEFORE
// computing current, counted vmcnt(4), raw s_barrier (no vmcnt(0) drain).
// EPI 0: store bf16 C (ldc).  EPI 1: store f32 C + resid (ldc).
template<int EPI>
__global__ __launch_bounds__(256)
void gemm_bt(const u16* __restrict__ A, const u16* __restrict__ Bt,
             void* __restrict__ Cp, const float* __restrict__ resid,
             int K, int ldc, int gx) {
  const int nwg = gridDim.x;
  const int q8 = nwg >> 3;
  const int swz = (blockIdx.x & 7) * q8 + (blockIdx.x >> 3);
  const int m0 = (swz / gx) * 128, n0 = (swz % gx) * 128;
  __shared__ __align__(16) u16 As[2][128*32];
  __shared__ __align__(16) u16 Bs[2][128*32];
  const int t = threadIdx.x, l = t & 63, w = t >> 6;
  const int wr = w >> 1, wc = w & 1;
  fx4 acc[4][4] = {};
  // staging: lane l of wave w -> LDS row (i*64 + w*16 + (l>>2)), col (l&3)*8 (linear)
  const int srow = l >> 2, scol = (l & 3) * 8;
  const u16* agp = A  + (size_t)(m0 + w*16 + srow)*K + scol;
  const u16* bgp = Bt + (size_t)(n0 + w*16 + srow)*K + scol;
  const int loff = (w*16 + srow)*32 + scol;   // u16 offset in LDS tile

  #define STAGE_G(bi, k0) do { \
    GLOAD(agp + (k0),            &As[bi][loff]); \
    GLOAD(agp + 64*K + (k0),     &As[bi][loff + 64*32]); \
    GLOAD(bgp + (k0),            &Bs[bi][loff]); \
    GLOAD(bgp + 64*K + (k0),     &Bs[bi][loff + 64*32]); \
  } while (0)

  #define COMPUTE_G(bi) do { \
    bf16x8 af[4], bfv[4]; \
    const u16* ap = &As[bi][(wr*64 + (l & 15))*32 + (l >> 4)*8]; \
    const u16* bp = &Bs[bi][(wc*64 + (l & 15))*32 + (l >> 4)*8]; \
    _Pragma("unroll") \
    for (int i = 0; i < 4; ++i) { \
      af[i]  = *(const bf16x8*)(ap + i*16*32); \
      bfv[i] = *(const bf16x8*)(bp + i*16*32); \
    } \
    _Pragma("unroll") \
    for (int mi = 0; mi < 4; ++mi) \
      _Pragma("unroll") \
      for (int ni = 0; ni < 4; ++ni) \
        acc[mi][ni] = __builtin_amdgcn_mfma_f32_16x16x32_bf16(af[mi], bfv[ni], acc[mi][ni], 0, 0, 0); \
  } while (0)

  const int NT = K >> 5;
  STAGE_G(0, 0);
  int cur = 0;
  for (int kt = 0; kt < NT-1; ++kt) {
    STAGE_G(cur^1, (kt+1)*32);
    asm volatile("s_waitcnt vmcnt(4)" ::: "memory");
    __builtin_amdgcn_s_barrier();
    asm volatile("" ::: "memory");
    COMPUTE_G(cur);
    asm volatile("" ::: "memory");
    __builtin_amdgcn_s_barrier();
    cur ^= 1;
  }
  asm volatile("s_waitcnt vmcnt(0)" ::: "memory");
  __builtin_amdgcn_s_barrier();
  asm volatile("" ::: "memory");
  COMPUTE_G(cur);
  #undef STAGE_G
  #undef COMPUTE_G

  const int rb = (l >> 4)*4, cb = l & 15;
  #pragma unroll
  for (int mi = 0; mi < 4; ++mi)
    #pragma unroll
    for (int ni = 0; ni < 4; ++ni) {
      const int col = n0 + wc*64 + ni*16 + cb;
      #pragma unroll
      for (int r = 0; r < 4; ++r) {
        const int row = m0 + wr*64 + mi*16 + rb + r;
        const size_t idx = (size_t)row*ldc + col;
        if (EPI == 0) ((u16*)Cp)[idx] = f2bf(acc[mi][ni][r]);
        else          ((float*)Cp)[idx] = acc[mi][ni][r] + resid[idx];
      }
    }
}

// ---------------------------------------------------------------- fused expand+GEGLU
// MERGED passes: per K-step stage A once + BOTH B tiles (pre rows 2304+n0e,
// lin rows 256+n0e) -> 32 MFMA per barrier-pair. Same T3-minimum 2-phase
// prefetch as gemm_bt (vmcnt(6): 6 loads/tile in flight).
// Output: lin*gelu(pre) -> A2 (bf16, e<1024) or Vv (f32, e>=1024).
__global__ __launch_bounds__(256)
void fused_expand(const u16* __restrict__ A, const u16* __restrict__ Bt,
                  u16* __restrict__ A2, float* __restrict__ Vv) {
  const int nwg = gridDim.x;                 // 3200
  const int q8 = nwg >> 3;
  const int swz = (blockIdx.x & 7) * q8 + (blockIdx.x >> 3);
  const int m0 = (swz >> 4) * 128;           // gx = 16
  const int n0e = (swz & 15) * 128;
  __shared__ __align__(16) u16 As[2][128*32];
  __shared__ __align__(16) u16 Bps[2][128*32];
  __shared__ __align__(16) u16 Bls[2][128*32];
  const int t = threadIdx.x, l = t & 63, w = t >> 6;
  const int wr = w >> 1, wc = w & 1;
  const int srow = l >> 2, scol = (l & 3) * 8;
  const u16* agp = A + (size_t)(m0 + w*16 + srow)*D_ + scol;
  const u16* bgp_pre = Bt + (size_t)(2*QK_ + E_ + n0e + w*16 + srow)*D_ + scol;
  const u16* bgp_lin = Bt + (size_t)(2*QK_ + n0e + w*16 + srow)*D_ + scol;
  const int loff = (w*16 + srow)*32 + scol;
  fx4 accp[4][4] = {};   // pre
  fx4 accl[4][4] = {};   // lin

  #define STAGE_F(bi, k0) do { \
    GLOAD(agp + (k0),               &As[bi][loff]); \
    GLOAD(agp + 64*D_ + (k0),       &As[bi][loff + 64*32]); \
    GLOAD(bgp_pre + (k0),           &Bps[bi][loff]); \
    GLOAD(bgp_pre + 64*D_ + (k0),   &Bps[bi][loff + 64*32]); \
    GLOAD(bgp_lin + (k0),           &Bls[bi][loff]); \
    GLOAD(bgp_lin + 64*D_ + (k0),   &Bls[bi][loff + 64*32]); \
  } while (0)

  #define COMPUTE_F(bi) do { \
    bf16x8 af[4], bfp[4], bfl[4]; \
    const u16* ap  = &As[bi][(wr*64 + (l & 15))*32 + (l >> 4)*8]; \
    const u16* bpp = &Bps[bi][(wc*64 + (l & 15))*32 + (l >> 4)*8]; \
    const u16* bpl = &Bls[bi][(wc*64 + (l & 15))*32 + (l >> 4)*8]; \
    _Pragma("unroll") \
    for (int i = 0; i < 4; ++i) { \
      af[i]  = *(const bf16x8*)(ap  + i*16*32); \
      bfp[i] = *(const bf16x8*)(bpp + i*16*32); \
      bfl[i] = *(const bf16x8*)(bpl + i*16*32); \
    } \
    _Pragma("unroll") \
    for (int mi = 0; mi < 4; ++mi) \
      _Pragma("unroll") \
      for (int ni = 0; ni < 4; ++ni) { \
        accp[mi][ni] = __builtin_amdgcn_mfma_f32_16x16x32_bf16(af[mi], bfp[ni], accp[mi][ni], 0, 0, 0); \
        accl[mi][ni] = __builtin_amdgcn_mfma_f32_16x16x32_bf16(af[mi], bfl[ni], accl[mi][ni], 0, 0, 0); \
      } \
  } while (0)

  const int NT = D_ >> 5;                    // 32
  STAGE_F(0, 0);
  int cur = 0;
  for (int kt = 0; kt < NT-1; ++kt) {
    STAGE_F(cur^1, (kt+1)*32);
    asm volatile("s_waitcnt vmcnt(6)" ::: "memory");
    __builtin_amdgcn_s_barrier();
    asm volatile("" ::: "memory");
    COMPUTE_F(cur);
    asm volatile("" ::: "memory");
    __builtin_amdgcn_s_barrier();
    cur ^= 1;
  }
  asm volatile("s_waitcnt vmcnt(0)" ::: "memory");
  __builtin_amdgcn_s_barrier();
  asm volatile("" ::: "memory");
  COMPUTE_F(cur);
  #undef STAGE_F
  #undef COMPUTE_F

  const int rb = (l >> 4)*4, cb = l & 15;
  #pragma unroll
  for (int mi = 0; mi < 4; ++mi)
    #pragma unroll
    for (int ni = 0; ni < 4; ++ni) {
      const int colc = wc*64 + ni*16 + cb;
      #pragma unroll
      for (int r = 0; r < 4; ++r) {
        const int row = m0 + wr*64 + mi*16 + rb + r;
        const float p = accp[mi][ni][r];
        const float g = 0.5f*p*(1.f + erff(p*0.70710678f));
        const float v = accl[mi][ni][r] * g;
        if (n0e < D_) A2[(size_t)row*E_ + n0e + colc] = f2bf(v);
        else          Vv[(size_t)row*D_ + (n0e - D_) + colc] = v;
      }
    }
}

// ---------------------------------------------------------------- attention
// block = (q-tile of 32 rows, batch). MFMA scores from compact QK buffer,
// fp32 softmax (8 lanes/row), fp32 PV with P broadcast from LDS + coalesced V.
__global__ __launch_bounds__(256)
void attn_kernel(const u16* __restrict__ QKb, const float* __restrict__ Vv,
                 const float* __restrict__ pbm, u16* __restrict__ A2) {
  const int b = blockIdx.y, qt = blockIdx.x;
  const int qbase = qt*32;
  const int kmax = (S_ < qbase+32) ? S_ : qbase+32;
  const int nkt = (kmax + 15) >> 4;
  const int t = threadIdx.x, l = t & 63, w = t >> 6;
  __shared__ float ScT[208][40];         // [k][qi], row stride 40 f32 (33 KB)
  float sp; { float p = pbm[0]; sp = (p > 20.f) ? p : log1pf(__expf(p)); }
  const float scale = 0.08838834764831845f;   // 1/sqrt(128)

  const int ntiles = 2*nkt;
  for (int tile = w; tile < ntiles; tile += 4) {
    const int qt16 = tile & 1, kt16 = tile >> 1;
    const int q0 = qbase + qt16*16, k0 = kt16*16;
    if (k0 > q0 + 15) continue;          // fully masked tile (zeroed in softmax tail)
    fx4 acc = {0.f, 0.f, 0.f, 0.f};
    const u16* qp = QKb + (size_t)(b*S_ + q0 + (l & 15))*256 + (l >> 4)*8;
    const u16* kp = QKb + (size_t)(b*S_ + k0 + (l & 15))*256 + QK_ + (l >> 4)*8;
    #pragma unroll
    for (int ks = 0; ks < 4; ++ks) {
      bf16x8 a  = *(const bf16x8*)(qp + ks*32);
      bf16x8 bb = *(const bf16x8*)(kp + ks*32);
      acc = __builtin_amdgcn_mfma_f32_16x16x32_bf16(a, bb, acc, 0, 0, 0);
    }
    const int kcol = k0 + (l & 15);
    #pragma unroll
    for (int r = 0; r < 4; ++r) {
      const int qg = q0 + (l >> 4)*4 + r;
      float s = acc[r]*scale + sp*(float)(kcol - qg);
      if (kcol > qg || qg >= S_ || kcol >= S_) s = -1e30f;
      ScT[kcol][qt16*16 + (l >> 4)*4 + r] = s;
    }
  }
  __syncthreads();
  {
    const int r = t >> 3, j = t & 7;     // 8 lanes per q-row
    const int qg = qbase + r;
    if (qg < S_) {
      float mx = -1e30f;
      for (int k = j; k <= qg; k += 8) mx = fmaxf(mx, ScT[k][r]);
      #pragma unroll
      for (int msk = 1; msk < 8; msk <<= 1) mx = fmaxf(mx, __shfl_xor(mx, msk));
      float sum = 0.f;
      for (int k = j; k <= qg; k += 8) { float p = __expf(ScT[k][r] - mx); ScT[k][r] = p; sum += p; }
      #pragma unroll
      for (int msk = 1; msk < 8; msk <<= 1) sum += __shfl_xor(sum, msk);
      const float inv = 1.f / sum;
      for (int k = j; k <= qg; k += 8) ScT[k][r] *= inv;
      for (int k = qg+1+j; k < kmax; k += 8) ScT[k][r] = 0.f;
    }
  }
  __syncthreads();
  // PV: wave w owns d-chunk [w*256, w*256+256); lane owns 4 d; 32 q-rows in regs.
  fx4 acc[32];
  #pragma unroll
  for (int i = 0; i < 32; ++i) acc[i] = (fx4){0.f,0.f,0.f,0.f};
  const float* vb = Vv + (size_t)b*S_*D_ + w*256 + l*4;
  for (int k = 0; k < kmax; ++k) {
    const fx4 v4 = *(const fx4*)(vb + (size_t)k*D_);
    #pragma unroll
    for (int g = 0; g < 8; ++g) {
      const fx4 p4 = *(const fx4*)&ScT[k][g*4];
      #pragma unroll
      for (int j = 0; j < 4; ++j) acc[g*4+j] += v4 * p4[j];
    }
  }
  #pragma unroll
  for (int qi = 0; qi < 32; ++qi) {
    const int qg = qbase + qi;
    if (qg < S_) {
      usx4 o;
      #pragma unroll
      for (int j = 0; j < 4; ++j) o[j] = f2bf(acc[qi][j]);
      *(usx4*)(A2 + (size_t)(b*S_ + qg)*E_ + D_ + w*256 + l*4) = o;
    }
  }
}

// ---------------------------------------------------------------- launch
extern "C" void kernel_launch(void* const* d_in, const int* in_sizes, int n_in,
                              void* d_out, int out_size, void* d_ws, size_t ws_size,
                              hipStream_t stream) {
  (void)in_sizes; (void)n_in; (void)out_size; (void)ws_size;
  const float* x   = (const float*)d_in[0];
  const float* ew  = (const float*)d_in[1];
  const float* pw  = (const float*)d_in[2];
  const float* gam = (const float*)d_in[3];
  const float* bet = (const float*)d_in[4];
  const float* pbm = (const float*)d_in[5];
  float* out = (float*)d_out;

  char* ws = (char*)d_ws;
  size_t off = 0;
  auto alloc = [&](size_t bytes) -> void* {
    void* p = ws + off; off += (bytes + 255) & ~(size_t)255; return p;
  };
  u16* xn  = (u16*)alloc((size_t)M_   * D_  * 2);   //  52.4 MB
  u16* QKb = (u16*)alloc((size_t)MPAD_* 256 * 2);   //  13.1 MB
  u16* A2  = (u16*)alloc((size_t)M_   * E_  * 2);   // 104.9 MB
  u16* ewb = (u16*)alloc((size_t)HE_  * D_  * 2);   //   8.9 MB
  u16* pwb = (u16*)alloc((size_t)D_   * E_  * 2);   //   4.2 MB  (total ~183.5 MB)
  float* Vv = out;                                  // V (f32 [M,D]) lives in d_out

  castw_kernel<<<1024, 256, 0, stream>>>(ew, pw, ewb, pwb);
  ln_kernel<<<M_, 256, 0, stream>>>(x, gam, bet, xn);
  gemm_bt<0><<<(256/128)*(M_/128), 256, 0, stream>>>(xn, ewb, QKb, nullptr, D_, 256, 256/128);
  fused_expand<<<(E_/128)*(M_/128), 256, 0, stream>>>(xn, ewb, A2, Vv);
  attn_kernel<<<dim3((S_+31)/32, B_), 256, 0, stream>>>(QKb, Vv, pbm, A2);
  gemm_bt<1><<<(D_/128)*(M_/128), 256, 0, stream>>>(A2, pwb, out, x, E_, D_, D_/128);
}